// Round 13
// baseline (143.365 us; speedup 1.0000x reference)
//
#include <hip/hip_runtime.h>

#define N 4096
#define NBINS 10            // bins 0..9 accumulated; bin 10 analytic
#define BLOCK 256
#define NSLOTS 64           // spread-atomic slots, 64 B apart
#define GROUPS 4            // 4 groups of 4 float4 per lane (64 elems/lane)
#define GF4 4

// R11 post-mortem: packed fp32 regressed — scalar fminf(fmaxf(u+l)) already
// folds to ONE v_add_f32 with VOP3 clamp modifier; explicit fmed3 blocked the
// fold. Reverted. This round: positives are ~1.5% dense (N_pos ~ 64/4096),
// so hc_pos leaves the main loop entirely -> main loop is hc_all only
// (~22 inst/elem vs 33); hc_pos accumulated in a sparse per-lane bit-walk
// over the label mask with L1-hot re-gather. Bit order == column order ->
// identical per-lane accumulation order -> absmax stays 0.

// Kernel A: cid recovery (validated R6-R11, absmax=0). cid[i] = column of
// first 1 in row i (ushort, 8 KB). Block 0 zeroes the atomic slots.
__global__ __launch_bounds__(BLOCK) void fastap_cid_kernel(
    const float* __restrict__ labels, unsigned short* __restrict__ cid,
    float* __restrict__ slots)
{
    if (blockIdx.x == 0 && threadIdx.x < NSLOTS)
        slots[threadIdx.x * 16] = 0.f;

    const int lane = threadIdx.x & 63;
    const int wid  = (blockIdx.x * BLOCK + threadIdx.x) >> 6;
    #pragma unroll
    for (int rr = 0; rr < 4; ++rr) {
        const int row = wid * 4 + rr;
        const float4* l4 = (const float4*)(labels + (size_t)row * N);
        bool done = false;
        for (int r = 0; !done; ++r) {                // terminates at diagonal
            float4 v = l4[r * 64 + lane];
            bool any = (v.x > 0.5f) || (v.y > 0.5f) || (v.z > 0.5f) || (v.w > 0.5f);
            unsigned long long m = __ballot(any);
            if (m) {
                int fl = __builtin_ctzll(m);
                if (lane == fl) {
                    int e = (v.x > 0.5f) ? 0 : (v.y > 0.5f) ? 1 : (v.z > 0.5f) ? 2 : 3;
                    cid[row] = (unsigned short)(r * 256 + lane * 4 + e);
                }
                done = true;
            }
        }
    }
}

// Kernel B: one row per wave, no barriers; mask-register labels; rolling
// prefetch with ONLY batch loads in the loop (R9 vmcnt-order fix); hc_all-only
// main loop + sparse positive post-pass.
__global__ __launch_bounds__(BLOCK) void fastap_row_kernel(
    const float* __restrict__ batch, const unsigned short* __restrict__ cid,
    float* __restrict__ slots)
{
    const int tid  = threadIdx.x;
    const int lane = tid & 63;
    const int row  = (blockIdx.x * BLOCK + tid) >> 6;   // global wave id

    const float*   brow = batch + (size_t)row * N;
    const float4*  b4 = (const float4*)brow;
    const ushort4* c4 = (const ushort4*)cid;            // 8 KB, cache-hot
    const int myc = (int)cid[row];                      // wave-uniform

    // --- prologue: cid loads FIRST (oldest in vmcnt order) ---
    ushort4 cv[16];
    #pragma unroll
    for (int j = 0; j < 16; ++j) cv[j] = c4[j * 64 + lane];

    // batch group-0 prefetch (youngest: outstanding during mask build)
    float4 buf[2][GF4];
    #pragma unroll
    for (int i = 0; i < GF4; ++i) buf[0][i] = b4[i * 64 + lane];

    // per-lane 64-bit label mask: bit (j*4+e) = (cid[j*256+lane*4+e] == myc)
    unsigned mlo = 0u, mhi = 0u;
    #pragma unroll
    for (int j = 0; j < 8; ++j) {
        mlo |= ((int)cv[j].x == myc ? 1u : 0u) << (j * 4 + 0);
        mlo |= ((int)cv[j].y == myc ? 1u : 0u) << (j * 4 + 1);
        mlo |= ((int)cv[j].z == myc ? 1u : 0u) << (j * 4 + 2);
        mlo |= ((int)cv[j].w == myc ? 1u : 0u) << (j * 4 + 3);
    }
    #pragma unroll
    for (int j = 8; j < 16; ++j) {
        mhi |= ((int)cv[j].x == myc ? 1u : 0u) << ((j - 8) * 4 + 0);
        mhi |= ((int)cv[j].y == myc ? 1u : 0u) << ((j - 8) * 4 + 1);
        mhi |= ((int)cv[j].z == myc ? 1u : 0u) << ((j - 8) * 4 + 2);
        mhi |= ((int)cv[j].w == myc ? 1u : 0u) << ((j - 8) * 4 + 3);
    }

    // --- main loop: hc_all ONLY (2 inst/bin: v_add+clamp, v_add) ---
    float hca[NBINS];
    #pragma unroll
    for (int l = 0; l < NBINS; ++l) hca[l] = 0.f;

    #pragma unroll
    for (int g = 0; g < GROUPS; ++g) {
        if (g + 1 < GROUPS) {   // rolling prefetch: only batch loads in loop
            #pragma unroll
            for (int i = 0; i < GF4; ++i)
                buf[(g + 1) & 1][i] = b4[((g + 1) * GF4 + i) * 64 + lane];
        }
        #pragma unroll
        for (int i = 0; i < GF4; ++i) {
            #pragma unroll
            for (int e = 0; e < 4; ++e) {
                float x = ((const float*)&buf[g & 1][i])[e];
                float u = fmaf(5.f, x, -4.f);     // 1 - dist2/Delta
                #pragma unroll
                for (int l = 0; l < NBINS; ++l)
                    hca[l] += fminf(fmaxf(u + (float)l, 0.f), 1.f); // add+clamp
            }
        }
    }

    // --- sparse positive pass: avg ~1 set bit/lane; row is L1-hot now ---
    float hcp[NBINS];
    #pragma unroll
    for (int l = 0; l < NBINS; ++l) hcp[l] = 0.f;

    unsigned long long m = ((unsigned long long)mhi << 32) | (unsigned long long)mlo;
    while (m) {                                   // bit order == column order
        int b = __builtin_ctzll(m);
        m &= m - 1;
        // bit b = j*4+e -> column j*256 + lane*4 + e
        float x = brow[(b >> 2) * 256 + lane * 4 + (b & 3)];
        float u = fmaf(5.f, x, -4.f);
        #pragma unroll
        for (int l = 0; l < NBINS; ++l)
            hcp[l] += fminf(fmaxf(u + (float)l, 0.f), 1.f);
    }

    float np = (float)(__popc(mlo) + __popc(mhi));

    // butterfly-reduce 21 accumulators across this wave's 64 lanes
    #pragma unroll
    for (int off = 1; off < 64; off <<= 1) {
        #pragma unroll
        for (int l = 0; l < NBINS; ++l) {
            hcp[l] += __shfl_xor(hcp[l], off, 64);
            hca[l] += __shfl_xor(hca[l], off, 64);
        }
        np += __shfl_xor(np, off, 64);
    }

    if (lane == 0) {
        float Hp_prev = 0.f, ap = 0.f;
        #pragma unroll
        for (int l = 0; l < NBINS; ++l) {
            float Hp = hcp[l];
            float Ha = hca[l];
            float hp = Hp - Hp_prev;
            if (Ha > 0.f) ap += hp * Hp / Ha;
            Hp_prev = Hp;
        }
        float Np = np;                                 // >= 1 (diagonal)
        ap += (Np - Hp_prev) * Np * (1.f / (float)N);  // analytic bin 10
        atomicAdd(&slots[(row & (NSLOTS - 1)) * 16], ap / Np);
    }
}

// Kernel C: one wave sums the 64 slots. loss = 1 - sum/N (all rows valid).
__global__ void fastap_finalize(const float* __restrict__ slots,
                                float* __restrict__ out)
{
    const int lane = threadIdx.x;
    float v = slots[lane * 16];
    #pragma unroll
    for (int off = 32; off > 0; off >>= 1)
        v += __shfl_down(v, off, 64);
    if (lane == 0) out[0] = 1.f - v * (1.f / (float)N);
}

extern "C" void kernel_launch(void* const* d_in, const int* in_sizes, int n_in,
                              void* d_out, int out_size, void* d_ws, size_t ws_size,
                              hipStream_t stream) {
    const float* batch  = (const float*)d_in[0];
    const float* labels = (const float*)d_in[1];
    unsigned short* cid = (unsigned short*)d_ws;        // 8 KB
    float* slots = (float*)((char*)d_ws + 8192);        // 64 slots, 64 B apart
    fastap_cid_kernel<<<N / (4 * 4), BLOCK, 0, stream>>>(labels, cid, slots);
    fastap_row_kernel<<<N / 4, BLOCK, 0, stream>>>(batch, cid, slots);
    fastap_finalize<<<1, 64, 0, stream>>>(slots, (float*)d_out);
}

// Round 14
// 140.960 us; speedup vs baseline: 1.0171x; 1.0171x over previous
//
#include <hip/hip_runtime.h>

#define N 4096
#define NBINS 10            // bins 0..9 accumulated; bin 10 analytic
#define BLOCK 256
#define NSLOTS 64           // spread-atomic slots, 64 B apart
#define GROUPS 4            // 4 groups of 4 float4 per lane (64 elems/lane)
#define GF4 4

typedef float float2v __attribute__((ext_vector_type(2)));

// R12 post-mortem: sparse-positive pass neutral (divergent bit-walk +
// uncoalesced gathers ate the dense-loop savings). Reverted to dense.
// R13: force VOP3P packed fp32 via inline asm — v_pk_fma_f32 with the VOP3P
// clamp bit computes clamp(5x+(l-4),0,1) for TWO elements in ONE inst
// (R11 failed because explicit fmed3 blocked the clamp fold and the
// compiler scalarized ext-vector float2 math). 3 packed inst/pair/bin vs
// 6 scalar. Even/odd pair partials merged pre-butterfly (R11 proved the
// reorder is absmax-0-safe).

// Kernel A: cid recovery (validated R6-R12, absmax=0). cid[i] = column of
// first 1 in row i (ushort, 8 KB). Block 0 zeroes the atomic slots.
__global__ __launch_bounds__(BLOCK) void fastap_cid_kernel(
    const float* __restrict__ labels, unsigned short* __restrict__ cid,
    float* __restrict__ slots)
{
    if (blockIdx.x == 0 && threadIdx.x < NSLOTS)
        slots[threadIdx.x * 16] = 0.f;

    const int lane = threadIdx.x & 63;
    const int wid  = (blockIdx.x * BLOCK + threadIdx.x) >> 6;
    #pragma unroll
    for (int rr = 0; rr < 4; ++rr) {
        const int row = wid * 4 + rr;
        const float4* l4 = (const float4*)(labels + (size_t)row * N);
        bool done = false;
        for (int r = 0; !done; ++r) {                // terminates at diagonal
            float4 v = l4[r * 64 + lane];
            bool any = (v.x > 0.5f) || (v.y > 0.5f) || (v.z > 0.5f) || (v.w > 0.5f);
            unsigned long long m = __ballot(any);
            if (m) {
                int fl = __builtin_ctzll(m);
                if (lane == fl) {
                    int e = (v.x > 0.5f) ? 0 : (v.y > 0.5f) ? 1 : (v.z > 0.5f) ? 2 : 3;
                    cid[row] = (unsigned short)(r * 256 + lane * 4 + e);
                }
                done = true;
            }
        }
    }
}

// Kernel B: one row per wave, no barriers; mask-register labels (R9);
// rolling prefetch with ONLY batch loads in the loop; packed-asm bin loop.
__global__ __launch_bounds__(BLOCK) void fastap_row_kernel(
    const float* __restrict__ batch, const unsigned short* __restrict__ cid,
    float* __restrict__ slots)
{
    const int tid  = threadIdx.x;
    const int lane = tid & 63;
    const int row  = (blockIdx.x * BLOCK + tid) >> 6;   // global wave id

    const float4*  b4 = (const float4*)(batch + (size_t)row * N);
    const ushort4* c4 = (const ushort4*)cid;            // 8 KB, cache-hot
    const int myc = (int)cid[row];                      // wave-uniform

    // --- prologue: cid loads FIRST (oldest in vmcnt order) ---
    ushort4 cv[16];
    #pragma unroll
    for (int j = 0; j < 16; ++j) cv[j] = c4[j * 64 + lane];

    // batch group-0 prefetch (youngest: outstanding during mask build)
    float4 buf[2][GF4];
    #pragma unroll
    for (int i = 0; i < GF4; ++i) buf[0][i] = b4[i * 64 + lane];

    // per-lane 64-bit label mask: bit (j*4+e) = (cid[j*256+lane*4+e] == myc)
    unsigned mlo = 0u, mhi = 0u;
    #pragma unroll
    for (int j = 0; j < 8; ++j) {
        mlo |= ((int)cv[j].x == myc ? 1u : 0u) << (j * 4 + 0);
        mlo |= ((int)cv[j].y == myc ? 1u : 0u) << (j * 4 + 1);
        mlo |= ((int)cv[j].z == myc ? 1u : 0u) << (j * 4 + 2);
        mlo |= ((int)cv[j].w == myc ? 1u : 0u) << (j * 4 + 3);
    }
    #pragma unroll
    for (int j = 8; j < 16; ++j) {
        mhi |= ((int)cv[j].x == myc ? 1u : 0u) << ((j - 8) * 4 + 0);
        mhi |= ((int)cv[j].y == myc ? 1u : 0u) << ((j - 8) * 4 + 1);
        mhi |= ((int)cv[j].z == myc ? 1u : 0u) << ((j - 8) * 4 + 2);
        mhi |= ((int)cv[j].w == myc ? 1u : 0u) << ((j - 8) * 4 + 3);
    }

    // packed constants: slope (5,5) and per-bin offset (l-4, l-4)
    float2v k5; k5.x = 5.f; k5.y = 5.f;
    float2v kl[NBINS];
    #pragma unroll
    for (int l = 0; l < NBINS; ++l) { kl[l].x = (float)l - 4.f; kl[l].y = (float)l - 4.f; }

    float2v hcp2[NBINS], hca2[NBINS];   // even/odd packed partials
    #pragma unroll
    for (int l = 0; l < NBINS; ++l) {
        hcp2[l].x = 0.f; hcp2[l].y = 0.f;
        hca2[l].x = 0.f; hca2[l].y = 0.f;
    }

    #pragma unroll
    for (int g = 0; g < GROUPS; ++g) {
        if (g + 1 < GROUPS) {   // rolling prefetch: only batch loads in loop
            #pragma unroll
            for (int i = 0; i < GF4; ++i)
                buf[(g + 1) & 1][i] = b4[((g + 1) * GF4 + i) * 64 + lane];
        }
        const unsigned mw = (g < 2) ? mlo : mhi;
        #pragma unroll
        for (int i = 0; i < GF4; ++i) {
            const float4 f = buf[g & 1][i];
            #pragma unroll
            for (int p = 0; p < 2; ++p) {           // two element-pairs per float4
                float2v x2;
                x2.x = (p == 0) ? f.x : f.z;
                x2.y = (p == 0) ? f.y : f.w;
                const unsigned bits = (mw >> ((g & 1) * 16 + i * 4 + 2 * p)) & 3u;
                float2v lbl2;
                lbl2.x = (float)(bits & 1u);
                lbl2.y = (float)(bits >> 1);
                #pragma unroll
                for (int l = 0; l < NBINS; ++l) {
                    float2v c;
                    // c = clamp(5*x + (l-4), 0, 1)  — fma + clamp fused, 2 elems
                    asm("v_pk_fma_f32 %0, %1, %2, %3 clamp"
                        : "=v"(c) : "v"(x2), "v"(k5), "v"(kl[l]));
                    asm("v_pk_add_f32 %0, %0, %1"
                        : "+v"(hca2[l]) : "v"(c));
                    asm("v_pk_fma_f32 %0, %1, %2, %0"
                        : "+v"(hcp2[l]) : "v"(c), "v"(lbl2));
                }
            }
        }
    }

    // merge even/odd partials, then butterfly 21 scalars across the wave
    float sp[NBINS], sa[NBINS];
    #pragma unroll
    for (int l = 0; l < NBINS; ++l) {
        sp[l] = hcp2[l].x + hcp2[l].y;
        sa[l] = hca2[l].x + hca2[l].y;
    }
    float np = (float)(__popc(mlo) + __popc(mhi));

    #pragma unroll
    for (int off = 1; off < 64; off <<= 1) {
        #pragma unroll
        for (int l = 0; l < NBINS; ++l) {
            sp[l] += __shfl_xor(sp[l], off, 64);
            sa[l] += __shfl_xor(sa[l], off, 64);
        }
        np += __shfl_xor(np, off, 64);
    }

    if (lane == 0) {
        float Hp_prev = 0.f, ap = 0.f;
        #pragma unroll
        for (int l = 0; l < NBINS; ++l) {
            float Hp = sp[l];
            float Ha = sa[l];
            float hp = Hp - Hp_prev;
            if (Ha > 0.f) ap += hp * Hp / Ha;
            Hp_prev = Hp;
        }
        float Np = np;                                 // >= 1 (diagonal)
        ap += (Np - Hp_prev) * Np * (1.f / (float)N);  // analytic bin 10
        atomicAdd(&slots[(row & (NSLOTS - 1)) * 16], ap / Np);
    }
}

// Kernel C: one wave sums the 64 slots. loss = 1 - sum/N (all rows valid).
__global__ void fastap_finalize(const float* __restrict__ slots,
                                float* __restrict__ out)
{
    const int lane = threadIdx.x;
    float v = slots[lane * 16];
    #pragma unroll
    for (int off = 32; off > 0; off >>= 1)
        v += __shfl_down(v, off, 64);
    if (lane == 0) out[0] = 1.f - v * (1.f / (float)N);
}

extern "C" void kernel_launch(void* const* d_in, const int* in_sizes, int n_in,
                              void* d_out, int out_size, void* d_ws, size_t ws_size,
                              hipStream_t stream) {
    const float* batch  = (const float*)d_in[0];
    const float* labels = (const float*)d_in[1];
    unsigned short* cid = (unsigned short*)d_ws;        // 8 KB
    float* slots = (float*)((char*)d_ws + 8192);        // 64 slots, 64 B apart
    fastap_cid_kernel<<<N / (4 * 4), BLOCK, 0, stream>>>(labels, cid, slots);
    fastap_row_kernel<<<N / 4, BLOCK, 0, stream>>>(batch, cid, slots);
    fastap_finalize<<<1, 64, 0, stream>>>(slots, (float*)d_out);
}